// Round 1
// baseline (733.601 us; speedup 1.0000x reference)
//
#include <hip/hip_runtime.h>
#include <math.h>

// Problem constants
#define BB 8
#define SS 512
#define LL 4096
#define EE 768
#define GEE 32
#define HDD 384
// LAMBDA_INIT = 0.8 - 0.6*exp(0) = 0.2 ; 1-LAMBDA_INIT = 0.8
#define LAM_INIT 0.2f
#define ONE_MINUS_LAM 0.8f
#define SCALING_F 0.05103103630798288f  // 384^-0.5

__device__ inline float waveMax(float v) {
#pragma unroll
    for (int o = 32; o > 0; o >>= 1) v = fmaxf(v, __shfl_xor(v, o));
    return v;
}
__device__ inline float waveMin(float v) {
#pragma unroll
    for (int o = 32; o > 0; o >>= 1) v = fminf(v, __shfl_xor(v, o));
    return v;
}
__device__ inline float waveSum(float v) {
#pragma unroll
    for (int o = 32; o > 0; o >>= 1) v += __shfl_xor(v, o);
    return v;
}

// ---------------------------------------------------------------------------
// K1: weight precombination.
//  blocks [0,192):  Wcomb[e*64 + h*32+g] = SCALING * sum_d Wq[e, h*384+d]*Wkv[g, h*384+d]
//  blocks [192,288): Wvo[g*768 + e] = sum_c Wkv[g,768+c]*ln[c]*Wout[c,e]
//  block 288: lam = exp(sum lq1*lk1) - exp(sum lq2*lk2) + 0.2
// ---------------------------------------------------------------------------
__global__ __launch_bounds__(256) void k1_prep(
    const float* __restrict__ Wq, const float* __restrict__ Wkv,
    const float* __restrict__ Wout, const float* __restrict__ lq1,
    const float* __restrict__ lk1, const float* __restrict__ lq2,
    const float* __restrict__ lk2, const float* __restrict__ ln,
    float* __restrict__ Wcomb, float* __restrict__ Wvo, float* __restrict__ lam)
{
    int blk = blockIdx.x;
    int tid = threadIdx.x;
    if (blk < 192) {
        int idx = blk * 256 + tid;      // [0, 49152)
        int e  = idx >> 6;
        int hg = idx & 63;
        int h = hg >> 5, g = hg & 31;
        const float4* wqr = (const float4*)(Wq  + (size_t)e * 768 + h * 384);
        const float4* wkr = (const float4*)(Wkv + (size_t)g * 1536 + h * 384);
        float s = 0.f;
        for (int d = 0; d < 96; ++d) {
            float4 a = wqr[d], b = wkr[d];
            s += a.x * b.x + a.y * b.y + a.z * b.z + a.w * b.w;
        }
        Wcomb[idx] = s * SCALING_F;
    } else if (blk < 288) {
        int idx = (blk - 192) * 256 + tid;  // [0, 24576)
        int g = idx / 768;
        int e = idx - g * 768;
        const float* wvr = Wkv + (size_t)g * 1536 + 768;
        float s = 0.f;
        for (int c = 0; c < 768; ++c)
            s += wvr[c] * ln[c] * Wout[(size_t)c * 768 + e];
        Wvo[idx] = s;
    } else {
        float s1 = 0.f, s2 = 0.f;
        for (int d = tid; d < 384; d += 256) {
            s1 += lq1[d] * lk1[d];
            s2 += lq2[d] * lk2[d];
        }
        s1 = waveSum(s1);
        s2 = waveSum(s2);
        __shared__ float r1[4], r2[4];
        int wid = tid >> 6, lane = tid & 63;
        if (lane == 0) { r1[wid] = s1; r2[wid] = s2; }
        __syncthreads();
        if (tid == 0) {
            float a  = r1[0] + r1[1] + r1[2] + r1[3];
            float b2 = r2[0] + r2[1] + r2[2] + r2[3];
            lam[0] = expf(a) - expf(b2) + LAM_INIT;
        }
    }
}

// ---------------------------------------------------------------------------
// K2: Qt[m, n] = query[m, :768] @ Wcomb[:768, n]   (M=4096, N=64, K=768)
// 128 blocks, tile 32m x 64n, BK=32, thread = 2m x 4n.
// ---------------------------------------------------------------------------
__global__ __launch_bounds__(256) void k2_qt(
    const float* __restrict__ query, const float* __restrict__ Wcomb,
    float* __restrict__ Qt)
{
    int m0 = blockIdx.x * 32;
    int tid = threadIdx.x;
    int tx = tid & 15;       // col group: cols tx*4 .. +3
    int ty = tid >> 4;       // row group: rows ty*2 .. +1
    __shared__ __align__(16) float As[32 * 36];  // 32 rows x 32 k, pad 36
    __shared__ __align__(16) float Bs[32 * 64];  // 32 k x 64 n
    float acc[2][4] = {{0.f,0.f,0.f,0.f},{0.f,0.f,0.f,0.f}};

    for (int k0 = 0; k0 < 768; k0 += 32) {
        __syncthreads();
#pragma unroll
        for (int q = 0; q < 4; ++q) {
            int idx = tid + q * 256;       // 1024 elems
            int r = idx >> 5, c = idx & 31;
            As[r * 36 + c] = query[(size_t)(m0 + r) * 768 + k0 + c];
        }
#pragma unroll
        for (int q = 0; q < 8; ++q) {
            int idx = tid + q * 256;       // 2048 elems
            int r = idx >> 6, c = idx & 63;
            Bs[r * 64 + c] = Wcomb[(size_t)(k0 + r) * 64 + c];
        }
        __syncthreads();
#pragma unroll
        for (int kk = 0; kk < 32; kk += 4) {
            float4 a0 = *(const float4*)&As[(ty * 2 + 0) * 36 + kk];
            float4 a1 = *(const float4*)&As[(ty * 2 + 1) * 36 + kk];
            float4 b0 = *(const float4*)&Bs[(kk + 0) * 64 + tx * 4];
            float4 b1 = *(const float4*)&Bs[(kk + 1) * 64 + tx * 4];
            float4 b2 = *(const float4*)&Bs[(kk + 2) * 64 + tx * 4];
            float4 b3 = *(const float4*)&Bs[(kk + 3) * 64 + tx * 4];
            acc[0][0] += a0.x*b0.x + a0.y*b1.x + a0.z*b2.x + a0.w*b3.x;
            acc[0][1] += a0.x*b0.y + a0.y*b1.y + a0.z*b2.y + a0.w*b3.y;
            acc[0][2] += a0.x*b0.z + a0.y*b1.z + a0.z*b2.z + a0.w*b3.z;
            acc[0][3] += a0.x*b0.w + a0.y*b1.w + a0.z*b2.w + a0.w*b3.w;
            acc[1][0] += a1.x*b0.x + a1.y*b1.x + a1.z*b2.x + a1.w*b3.x;
            acc[1][1] += a1.x*b0.y + a1.y*b1.y + a1.z*b2.y + a1.w*b3.y;
            acc[1][2] += a1.x*b0.z + a1.y*b1.z + a1.z*b2.z + a1.w*b3.z;
            acc[1][3] += a1.x*b0.w + a1.y*b1.w + a1.z*b2.w + a1.w*b3.w;
        }
    }
#pragma unroll
    for (int rr = 0; rr < 2; ++rr) {
        float4 o; o.x = acc[rr][0]; o.y = acc[rr][1]; o.z = acc[rr][2]; o.w = acc[rr][3];
        *(float4*)&Qt[(size_t)(m0 + ty * 2 + rr) * 64 + tx * 4] = o;
    }
}

// ---------------------------------------------------------------------------
// K3: fused scores -> masked softmax (2 heads) -> diff -> min-sub -> mask -> write
// One block per (b, 2 s-rows). 2048 blocks x 256 threads.
// Each thread owns 16 l-indices (l = tid + 256*i); p[h][ts][i] in registers.
// ---------------------------------------------------------------------------
__global__ __launch_bounds__(256) void k3_attn(
    const float* __restrict__ Qt, const float* __restrict__ key,
    const int* __restrict__ qmask, const int* __restrict__ kmask,
    const float* __restrict__ lamp, float* __restrict__ diffO)
{
    int blk = blockIdx.x;
    int b  = blk >> 8;
    int s0 = (blk & 255) * 2;
    int tid = threadIdx.x;
    int lane = tid & 63, wid = tid >> 6;

    __shared__ __align__(16) float qt_s[2][64];
    __shared__ float red[16];

    if (tid < 128) {
        int ts = tid >> 6, c = tid & 63;
        qt_s[ts][c] = Qt[(size_t)(b * 512 + s0 + ts) * 64 + c];
    }
    int qm0 = qmask[b * 512 + s0];
    int qm1 = qmask[b * 512 + s0 + 1];
    float lam = lamp[0];
    __syncthreads();

    float p[2][2][16];
    unsigned kmb = 0;

    // Phase A: scores (chunks of 2 l per thread to bound register pressure)
#pragma unroll
    for (int c = 0; c < 8; ++c) {
        float4 kf[2][8];
        int kmv[2];
#pragma unroll
        for (int u = 0; u < 2; ++u) {
            int i = 2 * c + u;
            int l = tid + (i << 8);
            const float4* kp = (const float4*)(key + ((size_t)(b * 4096 + l)) * 32);
#pragma unroll
            for (int q = 0; q < 8; ++q) kf[u][q] = kp[q];
            kmv[u] = kmask[b * 4096 + l];
            if (kmv[u]) kmb |= (1u << i);
        }
#pragma unroll
        for (int h = 0; h < 2; ++h) {
#pragma unroll
            for (int ts = 0; ts < 2; ++ts) {
                float a0 = 0.f, a1 = 0.f;
#pragma unroll
                for (int q = 0; q < 8; ++q) {
                    float4 qv = *(const float4*)&qt_s[ts][h * 32 + q * 4];
                    a0 += kf[0][q].x * qv.x; a0 += kf[0][q].y * qv.y;
                    a0 += kf[0][q].z * qv.z; a0 += kf[0][q].w * qv.w;
                    a1 += kf[1][q].x * qv.x; a1 += kf[1][q].y * qv.y;
                    a1 += kf[1][q].z * qv.z; a1 += kf[1][q].w * qv.w;
                }
                int qm = ts ? qm1 : qm0;
                p[h][ts][2 * c + 0] = (qm && kmv[0]) ? a0 : -1e20f;
                p[h][ts][2 * c + 1] = (qm && kmv[1]) ? a1 : -1e20f;
            }
        }
    }

    // Phase B1: row max
    float mrow[2][2];
#pragma unroll
    for (int h = 0; h < 2; ++h)
#pragma unroll
        for (int ts = 0; ts < 2; ++ts) {
            float v = -3.4e38f;
#pragma unroll
            for (int i = 0; i < 16; ++i) v = fmaxf(v, p[h][ts][i]);
            v = waveMax(v);
            if (lane == 0) red[(h * 2 + ts) * 4 + wid] = v;
        }
    __syncthreads();
#pragma unroll
    for (int h = 0; h < 2; ++h)
#pragma unroll
        for (int ts = 0; ts < 2; ++ts) {
            int r = (h * 2 + ts) * 4;
            mrow[h][ts] = fmaxf(fmaxf(red[r], red[r + 1]), fmaxf(red[r + 2], red[r + 3]));
        }
    __syncthreads();

    // Phase B2: exp + sum
    float inv[2][2];
#pragma unroll
    for (int h = 0; h < 2; ++h)
#pragma unroll
        for (int ts = 0; ts < 2; ++ts) {
            float s = 0.f;
#pragma unroll
            for (int i = 0; i < 16; ++i) {
                float e2 = __expf(p[h][ts][i] - mrow[h][ts]);
                p[h][ts][i] = e2;
                s += e2;
            }
            s = waveSum(s);
            if (lane == 0) red[(h * 2 + ts) * 4 + wid] = s;
        }
    __syncthreads();
#pragma unroll
    for (int h = 0; h < 2; ++h)
#pragma unroll
        for (int ts = 0; ts < 2; ++ts) {
            int r = (h * 2 + ts) * 4;
            inv[h][ts] = 1.0f / (red[r] + red[r + 1] + red[r + 2] + red[r + 3] + 1e-8f);
        }
    __syncthreads();

    // Phase C: diff + min (d stored over p[0][ts][i])
    float mn[2];
#pragma unroll
    for (int ts = 0; ts < 2; ++ts) {
        float v = 3.4e38f;
#pragma unroll
        for (int i = 0; i < 16; ++i) {
            float d = p[0][ts][i] * inv[0][ts] - lam * (p[1][ts][i] * inv[1][ts]);
            p[0][ts][i] = d;
            v = fminf(v, d);
        }
        v = waveMin(v);
        if (lane == 0) red[ts * 4 + wid] = v;
    }
    __syncthreads();
#pragma unroll
    for (int ts = 0; ts < 2; ++ts) {
        int r = ts * 4;
        mn[ts] = fminf(fminf(red[r], red[r + 1]), fminf(red[r + 2], red[r + 3]));
    }

    // Phase D: write diff output
#pragma unroll
    for (int ts = 0; ts < 2; ++ts) {
        int qm = ts ? qm1 : qm0;
        size_t base = (size_t)(b * 512 + s0 + ts) * 4096;
#pragma unroll
        for (int i = 0; i < 16; ++i) {
            int l = tid + (i << 8);
            float val = (qm && ((kmb >> i) & 1u)) ? (p[0][ts][i] - mn[ts] + 1e-20f) : 0.f;
            diffO[base + l] = val;
        }
    }
}

// ---------------------------------------------------------------------------
// K4: T[row, g] = sum_l diff[row, l] * key[b, l, g]   (rows=4096, g=32, K=4096)
// 512 blocks = 32 row-tiles(128) x 16 k-chunks(256). key tile in LDS,
// diff via vectorized global (L3-resident). atomicAdd epilogue (T pre-zeroed).
// ---------------------------------------------------------------------------
__global__ __launch_bounds__(256) void k4_T(
    const float* __restrict__ diff, const float* __restrict__ key,
    float* __restrict__ T)
{
    int blk = blockIdx.x;
    int rt = blk & 31, kc = blk >> 5;
    int row0 = rt << 7;     // *128
    int b = row0 >> 9;
    int l0 = kc << 8;       // *256
    int tid = threadIdx.x;
    int tx = tid & 7;       // g0 = tx*4
    int ty = tid >> 3;      // rows row0 + ty*4 + r
    int g0 = tx * 4;

    __shared__ __align__(16) float Ks[256][32];
#pragma unroll
    for (int q = 0; q < 32; ++q) {
        int idx = tid + (q << 8);
        int r = idx >> 5, g = idx & 31;
        Ks[r][g] = key[((size_t)(b * 4096 + l0 + r)) * 32 + g];
    }
    __syncthreads();

    float acc[4][4];
#pragma unroll
    for (int r = 0; r < 4; ++r)
#pragma unroll
        for (int c2 = 0; c2 < 4; ++c2) acc[r][c2] = 0.f;

    for (int j4 = 0; j4 < 64; ++j4) {
        int l = l0 + j4 * 4;
        float4 dv[4];
#pragma unroll
        for (int r = 0; r < 4; ++r)
            dv[r] = *(const float4*)(diff + (size_t)(row0 + ty * 4 + r) * 4096 + l);
#pragma unroll
        for (int jj = 0; jj < 4; ++jj) {
            float4 kq = *(const float4*)&Ks[j4 * 4 + jj][g0];
#pragma unroll
            for (int r = 0; r < 4; ++r) {
                float d = (jj == 0) ? dv[r].x : (jj == 1) ? dv[r].y : (jj == 2) ? dv[r].z : dv[r].w;
                acc[r][0] += d * kq.x;
                acc[r][1] += d * kq.y;
                acc[r][2] += d * kq.z;
                acc[r][3] += d * kq.w;
            }
        }
    }
#pragma unroll
    for (int r = 0; r < 4; ++r)
#pragma unroll
        for (int c2 = 0; c2 < 4; ++c2)
            atomicAdd(&T[(size_t)(row0 + ty * 4 + r) * 32 + g0 + c2], acc[r][c2]);
}

// ---------------------------------------------------------------------------
// K5: per-row RMS statistic from a = T@Wv, then out = 0.8*rs * (T @ Wvo)
// 512 blocks x 8 rows. Thread owns 3 e-columns.
// ---------------------------------------------------------------------------
__global__ __launch_bounds__(256) void k5_out(
    const float* __restrict__ T, const float* __restrict__ Wkv,
    const float* __restrict__ Wvo, float* __restrict__ out)
{
    int row0 = blockIdx.x * 8;
    int tid = threadIdx.x;
    int wid = tid >> 6, lane = tid & 63;
    __shared__ __align__(16) float Ts[8][32];
    __shared__ float red[8][4];
    __shared__ float rs_s[8];

    {
        int r = tid >> 5, g = tid & 31;
        Ts[r][g] = T[(size_t)(row0 + r) * 32 + g];
    }
    __syncthreads();

    float ssq[8];
#pragma unroll
    for (int r = 0; r < 8; ++r) ssq[r] = 0.f;

#pragma unroll
    for (int ec = 0; ec < 3; ++ec) {
        int e = tid + ec * 256;
        float wv[32];
#pragma unroll
        for (int g = 0; g < 32; ++g) wv[g] = Wkv[(size_t)g * 1536 + 768 + e];
#pragma unroll
        for (int r = 0; r < 8; ++r) {
            float a = 0.f;
#pragma unroll
            for (int g = 0; g < 32; ++g) a += Ts[r][g] * wv[g];
            ssq[r] += a * a;
        }
    }
#pragma unroll
    for (int r = 0; r < 8; ++r) {
        float v = waveSum(ssq[r]);
        if (lane == 0) red[r][wid] = v;
    }
    __syncthreads();
    if (tid < 8) {
        float s = red[tid][0] + red[tid][1] + red[tid][2] + red[tid][3];
        float ms = s * (1.0f / 768.0f);
        rs_s[tid] = rsqrtf(ms + 1e-5f) * ONE_MINUS_LAM;
    }
    __syncthreads();

#pragma unroll
    for (int ec = 0; ec < 3; ++ec) {
        int e = tid + ec * 256;
        float wo[32];
#pragma unroll
        for (int g = 0; g < 32; ++g) wo[g] = Wvo[(size_t)g * 768 + e];
#pragma unroll
        for (int r = 0; r < 8; ++r) {
            float o = 0.f;
#pragma unroll
            for (int g = 0; g < 32; ++g) o += Ts[r][g] * wo[g];
            out[(size_t)(row0 + r) * 768 + e] = o * rs_s[r];
        }
    }
}

// ---------------------------------------------------------------------------
extern "C" void kernel_launch(void* const* d_in, const int* in_sizes, int n_in,
                              void* d_out, int out_size, void* d_ws, size_t ws_size,
                              hipStream_t stream) {
    (void)in_sizes; (void)n_in; (void)out_size; (void)ws_size;
    const float* query = (const float*)d_in[0];
    const float* key   = (const float*)d_in[1];
    const int*   qmask = (const int*)d_in[2];
    const int*   kmask = (const int*)d_in[3];
    const float* Wq    = (const float*)d_in[4];
    const float* Wkv   = (const float*)d_in[5];
    const float* Wout  = (const float*)d_in[6];
    const float* lq1   = (const float*)d_in[7];
    const float* lk1   = (const float*)d_in[8];
    const float* lq2   = (const float*)d_in[9];
    const float* lk2   = (const float*)d_in[10];
    const float* ln    = (const float*)d_in[11];

    float* out  = (float*)d_out;          // (B,S,E) = 3,145,728 floats
    float* diff = out + 3145728;          // (B,S,L) = 16,777,216 floats

    float* ws    = (float*)d_ws;
    float* Wcomb = ws;                    // 49152
    float* Wvo   = ws + 49152;            // 24576
    float* lam   = ws + 73728;            // 1 (+pad to 64)
    float* Qt    = ws + 73792;            // 262144
    float* T     = ws + 335936;           // 131072

    hipMemsetAsync(T, 0, 131072 * sizeof(float), stream);
    k1_prep<<<289, 256, 0, stream>>>(Wq, Wkv, Wout, lq1, lk1, lq2, lk2, ln, Wcomb, Wvo, lam);
    k2_qt<<<128, 256, 0, stream>>>(query, Wcomb, Qt);
    k3_attn<<<2048, 256, 0, stream>>>(Qt, key, qmask, kmask, lam, diff);
    k4_T<<<512, 256, 0, stream>>>(diff, key, T);
    k5_out<<<512, 256, 0, stream>>>(T, Wkv, Wvo, out);
}

// Round 2
// 310.215 us; speedup vs baseline: 2.3648x; 2.3648x over previous
//
#include <hip/hip_runtime.h>
#include <math.h>

// Problem constants
#define BB 8
#define SS 512
#define LL 4096
#define EE 768
#define GEE 32
#define HDD 384
// LAMBDA_INIT = 0.8 - 0.6*exp(0) = 0.2 ; 1-LAMBDA_INIT = 0.8
#define LAM_INIT 0.2f
#define ONE_MINUS_LAM 0.8f
#define SCALING_F 0.05103103630798288f  // 384^-0.5

__device__ inline float waveMax(float v) {
#pragma unroll
    for (int o = 32; o > 0; o >>= 1) v = fmaxf(v, __shfl_xor(v, o));
    return v;
}
__device__ inline float waveMin(float v) {
#pragma unroll
    for (int o = 32; o > 0; o >>= 1) v = fminf(v, __shfl_xor(v, o));
    return v;
}
__device__ inline float waveSum(float v) {
#pragma unroll
    for (int o = 32; o > 0; o >>= 1) v += __shfl_xor(v, o);
    return v;
}

// ---------------------------------------------------------------------------
// K0: transpose key (B,L,32) -> keyT (B,32,L) for coalesced score loads.
// 128 blocks = 8 b x 16 l-tiles(256). LDS tile padded (stride 33).
// ---------------------------------------------------------------------------
__global__ __launch_bounds__(256) void k0_keyT(
    const float* __restrict__ key, float* __restrict__ keyT)
{
    int b  = blockIdx.x >> 4;
    int l0 = (blockIdx.x & 15) << 8;
    int tid = threadIdx.x;
    __shared__ float tile[256 * 33];
    const float* kp = key + ((size_t)b * 4096 + l0) * 32;
#pragma unroll
    for (int q = 0; q < 32; ++q) {
        int idx = tid + (q << 8);
        int r = idx >> 5, g = idx & 31;
        tile[r * 33 + g] = kp[idx];
    }
    __syncthreads();
    float* op = keyT + (size_t)b * 32 * 4096 + l0;
#pragma unroll
    for (int q = 0; q < 32; ++q) {
        int idx = tid + (q << 8);
        int g = idx >> 8, ll = idx & 255;
        op[(size_t)g * 4096 + ll] = tile[ll * 33 + g];
    }
}

// ---------------------------------------------------------------------------
// K1: weight precombination.
//  blocks [0,192):  Wcomb[e*64 + h*32+g] = SCALING * sum_d Wq[e, h*384+d]*Wkv[g, h*384+d]
//  blocks [192,288): Wvo[g*768 + e] = sum_c Wkv[g,768+c]*ln[c]*Wout[c,e]
//  block 288: lam = exp(sum lq1*lk1) - exp(sum lq2*lk2) + 0.2
// ---------------------------------------------------------------------------
__global__ __launch_bounds__(256) void k1_prep(
    const float* __restrict__ Wq, const float* __restrict__ Wkv,
    const float* __restrict__ Wout, const float* __restrict__ lq1,
    const float* __restrict__ lk1, const float* __restrict__ lq2,
    const float* __restrict__ lk2, const float* __restrict__ ln,
    float* __restrict__ Wcomb, float* __restrict__ Wvo, float* __restrict__ lam)
{
    int blk = blockIdx.x;
    int tid = threadIdx.x;
    if (blk < 192) {
        int idx = blk * 256 + tid;      // [0, 49152)
        int e  = idx >> 6;
        int hg = idx & 63;
        int h = hg >> 5, g = hg & 31;
        const float4* wqr = (const float4*)(Wq  + (size_t)e * 768 + h * 384);
        const float4* wkr = (const float4*)(Wkv + (size_t)g * 1536 + h * 384);
        float s = 0.f;
        for (int d = 0; d < 96; ++d) {
            float4 a = wqr[d], b = wkr[d];
            s += a.x * b.x + a.y * b.y + a.z * b.z + a.w * b.w;
        }
        Wcomb[idx] = s * SCALING_F;
    } else if (blk < 288) {
        int idx = (blk - 192) * 256 + tid;  // [0, 24576)
        int g = idx / 768;
        int e = idx - g * 768;
        const float* wvr = Wkv + (size_t)g * 1536 + 768;
        float s = 0.f;
        for (int c = 0; c < 768; ++c)
            s += wvr[c] * ln[c] * Wout[(size_t)c * 768 + e];
        Wvo[idx] = s;
    } else {
        float s1 = 0.f, s2 = 0.f;
        for (int d = tid; d < 384; d += 256) {
            s1 += lq1[d] * lk1[d];
            s2 += lq2[d] * lk2[d];
        }
        s1 = waveSum(s1);
        s2 = waveSum(s2);
        __shared__ float r1[4], r2[4];
        int wid = tid >> 6, lane = tid & 63;
        if (lane == 0) { r1[wid] = s1; r2[wid] = s2; }
        __syncthreads();
        if (tid == 0) {
            float a  = r1[0] + r1[1] + r1[2] + r1[3];
            float b2 = r2[0] + r2[1] + r2[2] + r2[3];
            lam[0] = expf(a) - expf(b2) + LAM_INIT;
        }
    }
}

// ---------------------------------------------------------------------------
// K2: Qt[m, n] = query[m, :768] @ Wcomb[:768, n]   (M=4096, N=64, K=768)
// 128 blocks, tile 32m x 64n, BK=32, thread = 2m x 4n.
// ---------------------------------------------------------------------------
__global__ __launch_bounds__(256) void k2_qt(
    const float* __restrict__ query, const float* __restrict__ Wcomb,
    float* __restrict__ Qt)
{
    int m0 = blockIdx.x * 32;
    int tid = threadIdx.x;
    int tx = tid & 15;       // col group: cols tx*4 .. +3
    int ty = tid >> 4;       // row group: rows ty*2 .. +1
    __shared__ __align__(16) float As[32 * 36];  // 32 rows x 32 k, pad 36
    __shared__ __align__(16) float Bs[32 * 64];  // 32 k x 64 n
    float acc[2][4] = {{0.f,0.f,0.f,0.f},{0.f,0.f,0.f,0.f}};

    for (int k0 = 0; k0 < 768; k0 += 32) {
        __syncthreads();
#pragma unroll
        for (int q = 0; q < 4; ++q) {
            int idx = tid + q * 256;       // 1024 elems
            int r = idx >> 5, c = idx & 31;
            As[r * 36 + c] = query[(size_t)(m0 + r) * 768 + k0 + c];
        }
#pragma unroll
        for (int q = 0; q < 8; ++q) {
            int idx = tid + q * 256;       // 2048 elems
            int r = idx >> 6, c = idx & 63;
            Bs[r * 64 + c] = Wcomb[(size_t)(k0 + r) * 64 + c];
        }
        __syncthreads();
#pragma unroll
        for (int kk = 0; kk < 32; kk += 4) {
            float4 a0 = *(const float4*)&As[(ty * 2 + 0) * 36 + kk];
            float4 a1 = *(const float4*)&As[(ty * 2 + 1) * 36 + kk];
            float4 b0 = *(const float4*)&Bs[(kk + 0) * 64 + tx * 4];
            float4 b1 = *(const float4*)&Bs[(kk + 1) * 64 + tx * 4];
            float4 b2 = *(const float4*)&Bs[(kk + 2) * 64 + tx * 4];
            float4 b3 = *(const float4*)&Bs[(kk + 3) * 64 + tx * 4];
            acc[0][0] += a0.x*b0.x + a0.y*b1.x + a0.z*b2.x + a0.w*b3.x;
            acc[0][1] += a0.x*b0.y + a0.y*b1.y + a0.z*b2.y + a0.w*b3.y;
            acc[0][2] += a0.x*b0.z + a0.y*b1.z + a0.z*b2.z + a0.w*b3.z;
            acc[0][3] += a0.x*b0.w + a0.y*b1.w + a0.z*b2.w + a0.w*b3.w;
            acc[1][0] += a1.x*b0.x + a1.y*b1.x + a1.z*b2.x + a1.w*b3.x;
            acc[1][1] += a1.x*b0.y + a1.y*b1.y + a1.z*b2.y + a1.w*b3.y;
            acc[1][2] += a1.x*b0.z + a1.y*b1.z + a1.z*b2.z + a1.w*b3.z;
            acc[1][3] += a1.x*b0.w + a1.y*b1.w + a1.z*b2.w + a1.w*b3.w;
        }
    }
#pragma unroll
    for (int rr = 0; rr < 2; ++rr) {
        float4 o; o.x = acc[rr][0]; o.y = acc[rr][1]; o.z = acc[rr][2]; o.w = acc[rr][3];
        *(float4*)&Qt[(size_t)(m0 + ty * 2 + rr) * 64 + tx * 4] = o;
    }
}

// ---------------------------------------------------------------------------
// K3 v2: fused scores -> masked softmax (2 heads) -> diff -> min-sub -> write.
// One block per (b, 2 s-rows). 2048 blocks x 256 threads.
// Outer-product over g using keyT: coalesced float4 key loads, qt via LDS
// broadcast, p[2][2][16] in registers (~100 VGPR, no spill).
// Thread owns l = c*1024 + tid*4 + j   (c<4, j<4).
// ---------------------------------------------------------------------------
__global__ __launch_bounds__(256, 4) void k3_attn(
    const float* __restrict__ Qt, const float* __restrict__ keyT,
    const int* __restrict__ qmask, const int* __restrict__ kmask,
    const float* __restrict__ lamp, float* __restrict__ diffO)
{
    int blk = blockIdx.x;
    int b  = blk >> 8;
    int s0 = (blk & 255) * 2;
    int tid = threadIdx.x;
    int lane = tid & 63, wid = tid >> 6;

    __shared__ float qt_s[128];   // [ts*64 + h*32 + g]
    __shared__ float red[16];

    if (tid < 128) {
        int ts = tid >> 6, c2 = tid & 63;
        qt_s[tid] = Qt[(size_t)(b * 512 + s0 + ts) * 64 + c2];
    }
    int qm0 = qmask[b * 512 + s0];
    int qm1 = qmask[b * 512 + s0 + 1];
    float lam = lamp[0];

    // kmask bits for the 16 owned l's
    unsigned kmb = 0;
#pragma unroll
    for (int c = 0; c < 4; ++c) {
        int4 km = *(const int4*)(kmask + b * 4096 + c * 1024 + tid * 4);
        if (km.x) kmb |= 1u << (c * 4 + 0);
        if (km.y) kmb |= 1u << (c * 4 + 1);
        if (km.z) kmb |= 1u << (c * 4 + 2);
        if (km.w) kmb |= 1u << (c * 4 + 3);
    }
    __syncthreads();

    float p[2][2][16];   // [h][ts][c*4+j]
#pragma unroll
    for (int h = 0; h < 2; ++h)
#pragma unroll
        for (int ts = 0; ts < 2; ++ts)
#pragma unroll
            for (int i = 0; i < 16; ++i) p[h][ts][i] = 0.f;

    const float* kt = keyT + (size_t)b * 32 * 4096 + tid * 4;
    for (int g = 0; g < 32; ++g) {
        float q00 = qt_s[g];          // ts0 h0
        float q01 = qt_s[32 + g];     // ts0 h1
        float q10 = qt_s[64 + g];     // ts1 h0
        float q11 = qt_s[96 + g];     // ts1 h1
        const float* kg = kt + (size_t)g * 4096;
#pragma unroll
        for (int c = 0; c < 4; ++c) {
            float4 kv = *(const float4*)(kg + c * 1024);
            p[0][0][c*4+0] += q00 * kv.x; p[0][0][c*4+1] += q00 * kv.y;
            p[0][0][c*4+2] += q00 * kv.z; p[0][0][c*4+3] += q00 * kv.w;
            p[1][0][c*4+0] += q01 * kv.x; p[1][0][c*4+1] += q01 * kv.y;
            p[1][0][c*4+2] += q01 * kv.z; p[1][0][c*4+3] += q01 * kv.w;
            p[0][1][c*4+0] += q10 * kv.x; p[0][1][c*4+1] += q10 * kv.y;
            p[0][1][c*4+2] += q10 * kv.z; p[0][1][c*4+3] += q10 * kv.w;
            p[1][1][c*4+0] += q11 * kv.x; p[1][1][c*4+1] += q11 * kv.y;
            p[1][1][c*4+2] += q11 * kv.z; p[1][1][c*4+3] += q11 * kv.w;
        }
    }

    // apply masks
#pragma unroll
    for (int h = 0; h < 2; ++h)
#pragma unroll
        for (int ts = 0; ts < 2; ++ts) {
            int qm = ts ? qm1 : qm0;
#pragma unroll
            for (int i = 0; i < 16; ++i) {
                bool ok = qm && ((kmb >> i) & 1u);
                p[h][ts][i] = ok ? p[h][ts][i] : -1e20f;
            }
        }

    // Phase B1: row max
    float mrow[2][2];
#pragma unroll
    for (int h = 0; h < 2; ++h)
#pragma unroll
        for (int ts = 0; ts < 2; ++ts) {
            float v = -3.4e38f;
#pragma unroll
            for (int i = 0; i < 16; ++i) v = fmaxf(v, p[h][ts][i]);
            v = waveMax(v);
            if (lane == 0) red[(h * 2 + ts) * 4 + wid] = v;
        }
    __syncthreads();
#pragma unroll
    for (int h = 0; h < 2; ++h)
#pragma unroll
        for (int ts = 0; ts < 2; ++ts) {
            int r = (h * 2 + ts) * 4;
            mrow[h][ts] = fmaxf(fmaxf(red[r], red[r + 1]), fmaxf(red[r + 2], red[r + 3]));
        }
    __syncthreads();

    // Phase B2: exp + sum
    float inv[2][2];
#pragma unroll
    for (int h = 0; h < 2; ++h)
#pragma unroll
        for (int ts = 0; ts < 2; ++ts) {
            float s = 0.f;
#pragma unroll
            for (int i = 0; i < 16; ++i) {
                float e2 = __expf(p[h][ts][i] - mrow[h][ts]);
                p[h][ts][i] = e2;
                s += e2;
            }
            s = waveSum(s);
            if (lane == 0) red[(h * 2 + ts) * 4 + wid] = s;
        }
    __syncthreads();
#pragma unroll
    for (int h = 0; h < 2; ++h)
#pragma unroll
        for (int ts = 0; ts < 2; ++ts) {
            int r = (h * 2 + ts) * 4;
            inv[h][ts] = 1.0f / (red[r] + red[r + 1] + red[r + 2] + red[r + 3] + 1e-8f);
        }
    __syncthreads();

    // Phase C: diff + min (d stored over p[0][ts][i])
    float mn[2];
#pragma unroll
    for (int ts = 0; ts < 2; ++ts) {
        float v = 3.4e38f;
#pragma unroll
        for (int i = 0; i < 16; ++i) {
            float d = p[0][ts][i] * inv[0][ts] - lam * (p[1][ts][i] * inv[1][ts]);
            p[0][ts][i] = d;
            v = fminf(v, d);
        }
        v = waveMin(v);
        if (lane == 0) red[ts * 4 + wid] = v;
    }
    __syncthreads();
#pragma unroll
    for (int ts = 0; ts < 2; ++ts) {
        int r = ts * 4;
        mn[ts] = fminf(fminf(red[r], red[r + 1]), fminf(red[r + 2], red[r + 3]));
    }

    // Phase D: write diff output (float4, coalesced)
#pragma unroll
    for (int ts = 0; ts < 2; ++ts) {
        int qm = ts ? qm1 : qm0;
        size_t base = (size_t)(b * 512 + s0 + ts) * 4096 + tid * 4;
#pragma unroll
        for (int c = 0; c < 4; ++c) {
            float4 o;
            float v0 = p[0][ts][c*4+0] - mn[ts] + 1e-20f;
            float v1 = p[0][ts][c*4+1] - mn[ts] + 1e-20f;
            float v2 = p[0][ts][c*4+2] - mn[ts] + 1e-20f;
            float v3 = p[0][ts][c*4+3] - mn[ts] + 1e-20f;
            o.x = (qm && ((kmb >> (c*4+0)) & 1u)) ? v0 : 0.f;
            o.y = (qm && ((kmb >> (c*4+1)) & 1u)) ? v1 : 0.f;
            o.z = (qm && ((kmb >> (c*4+2)) & 1u)) ? v2 : 0.f;
            o.w = (qm && ((kmb >> (c*4+3)) & 1u)) ? v3 : 0.f;
            *(float4*)(diffO + base + c * 1024) = o;
        }
    }
}

// ---------------------------------------------------------------------------
// K4: T[row, g] = sum_l diff[row, l] * key[b, l, g]   (rows=4096, g=32, K=4096)
// 512 blocks = 32 row-tiles(128) x 16 k-chunks(256). key tile in LDS,
// diff via vectorized global (L3-resident). atomicAdd epilogue (T pre-zeroed).
// ---------------------------------------------------------------------------
__global__ __launch_bounds__(256) void k4_T(
    const float* __restrict__ diff, const float* __restrict__ key,
    float* __restrict__ T)
{
    int blk = blockIdx.x;
    int rt = blk & 31, kc = blk >> 5;
    int row0 = rt << 7;     // *128
    int b = row0 >> 9;
    int l0 = kc << 8;       // *256
    int tid = threadIdx.x;
    int tx = tid & 7;       // g0 = tx*4
    int ty = tid >> 3;      // rows row0 + ty*4 + r
    int g0 = tx * 4;

    __shared__ __align__(16) float Ks[256][32];
#pragma unroll
    for (int q = 0; q < 32; ++q) {
        int idx = tid + (q << 8);
        int r = idx >> 5, g = idx & 31;
        Ks[r][g] = key[((size_t)(b * 4096 + l0 + r)) * 32 + g];
    }
    __syncthreads();

    float acc[4][4];
#pragma unroll
    for (int r = 0; r < 4; ++r)
#pragma unroll
        for (int c2 = 0; c2 < 4; ++c2) acc[r][c2] = 0.f;

    for (int j4 = 0; j4 < 64; ++j4) {
        int l = l0 + j4 * 4;
        float4 dv[4];
#pragma unroll
        for (int r = 0; r < 4; ++r)
            dv[r] = *(const float4*)(diff + (size_t)(row0 + ty * 4 + r) * 4096 + l);
#pragma unroll
        for (int jj = 0; jj < 4; ++jj) {
            float4 kq = *(const float4*)&Ks[j4 * 4 + jj][g0];
#pragma unroll
            for (int r = 0; r < 4; ++r) {
                float d = (jj == 0) ? dv[r].x : (jj == 1) ? dv[r].y : (jj == 2) ? dv[r].z : dv[r].w;
                acc[r][0] += d * kq.x;
                acc[r][1] += d * kq.y;
                acc[r][2] += d * kq.z;
                acc[r][3] += d * kq.w;
            }
        }
    }
#pragma unroll
    for (int r = 0; r < 4; ++r)
#pragma unroll
        for (int c2 = 0; c2 < 4; ++c2)
            atomicAdd(&T[(size_t)(row0 + ty * 4 + r) * 32 + g0 + c2], acc[r][c2]);
}

// ---------------------------------------------------------------------------
// K5: per-row RMS statistic from a = T@Wv, then out = 0.8*rs * (T @ Wvo)
// 512 blocks x 8 rows. Thread owns 3 e-columns.
// ---------------------------------------------------------------------------
__global__ __launch_bounds__(256) void k5_out(
    const float* __restrict__ T, const float* __restrict__ Wkv,
    const float* __restrict__ Wvo, float* __restrict__ out)
{
    int row0 = blockIdx.x * 8;
    int tid = threadIdx.x;
    int wid = tid >> 6, lane = tid & 63;
    __shared__ __align__(16) float Ts[8][32];
    __shared__ float red[8][4];
    __shared__ float rs_s[8];

    {
        int r = tid >> 5, g = tid & 31;
        Ts[r][g] = T[(size_t)(row0 + r) * 32 + g];
    }
    __syncthreads();

    float ssq[8];
#pragma unroll
    for (int r = 0; r < 8; ++r) ssq[r] = 0.f;

#pragma unroll
    for (int ec = 0; ec < 3; ++ec) {
        int e = tid + ec * 256;
        float wv[32];
#pragma unroll
        for (int g = 0; g < 32; ++g) wv[g] = Wkv[(size_t)g * 1536 + 768 + e];
#pragma unroll
        for (int r = 0; r < 8; ++r) {
            float a = 0.f;
#pragma unroll
            for (int g = 0; g < 32; ++g) a += Ts[r][g] * wv[g];
            ssq[r] += a * a;
        }
    }
#pragma unroll
    for (int r = 0; r < 8; ++r) {
        float v = waveSum(ssq[r]);
        if (lane == 0) red[r][wid] = v;
    }
    __syncthreads();
    if (tid < 8) {
        float s = red[tid][0] + red[tid][1] + red[tid][2] + red[tid][3];
        float ms = s * (1.0f / 768.0f);
        rs_s[tid] = rsqrtf(ms + 1e-5f) * ONE_MINUS_LAM;
    }
    __syncthreads();

#pragma unroll
    for (int ec = 0; ec < 3; ++ec) {
        int e = tid + ec * 256;
        float wo[32];
#pragma unroll
        for (int g = 0; g < 32; ++g) wo[g] = Wvo[(size_t)g * 768 + e];
#pragma unroll
        for (int r = 0; r < 8; ++r) {
            float o = 0.f;
#pragma unroll
            for (int g = 0; g < 32; ++g) o += Ts[r][g] * wo[g];
            out[(size_t)(row0 + r) * 768 + e] = o * rs_s[r];
        }
    }
}

// ---------------------------------------------------------------------------
extern "C" void kernel_launch(void* const* d_in, const int* in_sizes, int n_in,
                              void* d_out, int out_size, void* d_ws, size_t ws_size,
                              hipStream_t stream) {
    (void)in_sizes; (void)n_in; (void)out_size; (void)ws_size;
    const float* query = (const float*)d_in[0];
    const float* key   = (const float*)d_in[1];
    const int*   qmask = (const int*)d_in[2];
    const int*   kmask = (const int*)d_in[3];
    const float* Wq    = (const float*)d_in[4];
    const float* Wkv   = (const float*)d_in[5];
    const float* Wout  = (const float*)d_in[6];
    const float* lq1   = (const float*)d_in[7];
    const float* lk1   = (const float*)d_in[8];
    const float* lq2   = (const float*)d_in[9];
    const float* lk2   = (const float*)d_in[10];
    const float* ln    = (const float*)d_in[11];

    float* out  = (float*)d_out;          // (B,S,E) = 3,145,728 floats
    float* diff = out + 3145728;          // (B,S,L) = 16,777,216 floats

    float* ws    = (float*)d_ws;
    float* Wcomb = ws;                    // 49152
    float* Wvo   = ws + 49152;            // 24576
    float* lam   = ws + 73728;            // 64 (1 used)
    float* Qt    = ws + 73792;            // 262144
    float* T     = ws + 335936;           // 131072
    float* keyT  = ws + 467008;           // 1048576  -> total ~6.1 MB

    hipMemsetAsync(T, 0, 131072 * sizeof(float), stream);
    k1_prep<<<289, 256, 0, stream>>>(Wq, Wkv, Wout, lq1, lk1, lq2, lk2, ln, Wcomb, Wvo, lam);
    k0_keyT<<<128, 256, 0, stream>>>(key, keyT);
    k2_qt<<<128, 256, 0, stream>>>(query, Wcomb, Qt);
    k3_attn<<<2048, 256, 0, stream>>>(Qt, keyT, qmask, kmask, lam, diff);
    k4_T<<<512, 256, 0, stream>>>(diff, key, T);
    k5_out<<<512, 256, 0, stream>>>(T, Wkv, Wvo, out);
}